// Round 1
// baseline (320.399 us; speedup 1.0000x reference)
//
#include <hip/hip_runtime.h>

typedef unsigned short u16;
typedef unsigned int u32;
typedef __bf16 bf16x8 __attribute__((ext_vector_type(8)));
typedef float f32x4 __attribute__((ext_vector_type(4)));

#define B_ 16
#define C_ 512
#define N_ 1024
#define NB_ 16384   // B_*N_
#define K_ 512
#define M3_ 1536

// ---- helpers ----
__device__ __forceinline__ u16 f2bf(float f) {
  u32 u = __float_as_uint(f);
  u32 r = (u + 0x7FFFu + ((u >> 16) & 1u)) >> 16;  // RNE
  return (u16)r;
}

// async global->LDS, 16B per lane. LDS dest must be wave-uniform base (+lane*16 implicit).
__device__ __forceinline__ void gl_lds16(const void* g, void* l) {
  __builtin_amdgcn_global_load_lds(
      (const __attribute__((address_space(1))) u32*)(uintptr_t)g,
      (__attribute__((address_space(3))) u32*)(u32)(uintptr_t)l, 16, 0, 0);
}

// ---- kernel 1: fp32 -> bf16 cast for weights ----
__global__ __launch_bounds__(256) void cast_bf16_kernel(const float* __restrict__ src,
                                                        u16* __restrict__ dst, int n) {
  int i = blockIdx.x * 256 + threadIdx.x;
  if (i < n) dst[i] = f2bf(src[i]);
}

// ---- kernel 2: GroupNorm, writes h^T as (B*N, C) bf16 ----
__global__ __launch_bounds__(256) void gnorm_kernel(const float* __restrict__ x,
                                                    const float* __restrict__ gamma,
                                                    const float* __restrict__ beta,
                                                    u16* __restrict__ ht) {
  int blk = blockIdx.x;
  int b = blk >> 5, g = blk & 31;
  int t = threadIdx.x;
  const float* xb = x + ((size_t)(b * C_ + g * 16) << 10);
  float v[16][4];
  float s = 0.f, sq = 0.f;
#pragma unroll
  for (int cc = 0; cc < 16; ++cc) {
#pragma unroll
    for (int r = 0; r < 4; ++r) {
      float f = xb[cc * 1024 + r * 256 + t];
      v[cc][r] = f; s += f; sq += f * f;
    }
  }
#pragma unroll
  for (int m = 32; m >= 1; m >>= 1) { s += __shfl_xor(s, m, 64); sq += __shfl_xor(sq, m, 64); }
  __shared__ float red[8];
  int w = t >> 6;
  if ((t & 63) == 0) { red[w * 2] = s; red[w * 2 + 1] = sq; }
  __syncthreads();
  s = red[0] + red[2] + red[4] + red[6];
  sq = red[1] + red[3] + red[5] + red[7];
  float mean = s * (1.f / 16384.f);
  float var = sq * (1.f / 16384.f) - mean * mean;
  float rstd = rsqrtf(var + 1e-5f);
  float gm[16], bt[16];
#pragma unroll
  for (int cc = 0; cc < 16; ++cc) {
    gm[cc] = gamma[g * 16 + cc] * rstd;
    bt[cc] = beta[g * 16 + cc];
  }
  u16* hb = ht + ((size_t)(b << 10)) * C_ + g * 16;
#pragma unroll
  for (int r = 0; r < 4; ++r) {
    u32 pk[8];
#pragma unroll
    for (int q = 0; q < 8; ++q) {
      float f0 = (v[2 * q][r] - mean) * gm[2 * q] + bt[2 * q];
      float f1 = (v[2 * q + 1][r] - mean) * gm[2 * q + 1] + bt[2 * q + 1];
      pk[q] = (u32)f2bf(f0) | ((u32)f2bf(f1) << 16);
    }
    u16* dp = hb + (size_t)(r * 256 + t) * C_;
    uint4 a = {pk[0], pk[1], pk[2], pk[3]};
    uint4 b4 = {pk[4], pk[5], pk[6], pk[7]};
    *(uint4*)dp = a;
    *(uint4*)(dp + 8) = b4;
  }
}

// ---- GEMM: C[MxNB] = A[MxK] * BT[NBxK]^T ; 128x128 tile, BK=64, 4 waves ----
// EPI 0: out bf16 (o, bn) + bias   EPI 1: out = x + val + bias -> fp32 (b,c,n)
template <int EPI>
__global__ __launch_bounds__(256) void gemm_kernel(const u16* __restrict__ A,
                                                   const u16* __restrict__ BT,
                                                   const float* __restrict__ bias,
                                                   u16* __restrict__ Co,
                                                   const float* __restrict__ xres,
                                                   float* __restrict__ Fo) {
  __shared__ u16 ldsA[128 * 64];
  __shared__ u16 ldsB[128 * 64];
  int t = threadIdx.x;
  int l = t & 63, w = t >> 6;
  int wr = w >> 1, wc = w & 1;
  int ro0 = blockIdx.y * 128, co0 = blockIdx.x * 128;
  f32x4 acc[4][4];
#pragma unroll
  for (int m = 0; m < 4; ++m)
#pragma unroll
    for (int n = 0; n < 4; ++n) acc[m][n] = {0.f, 0.f, 0.f, 0.f};
  int srow = t >> 3, sg = t & 7;
  for (int kt = 0; kt < 8; ++kt) {
    int k0 = kt * 64;
#pragma unroll
    for (int i = 0; i < 4; ++i) {
      int row = i * 32 + srow;
      int gl = sg ^ (row & 7);  // pre-swizzled source -> swizzled linear LDS
      gl_lds16(A + (size_t)(ro0 + row) * K_ + k0 + gl * 8, ldsA + (i * 32 + w * 8) * 64);
      gl_lds16(BT + (size_t)(co0 + row) * K_ + k0 + gl * 8, ldsB + (i * 32 + w * 8) * 64);
    }
    __syncthreads();
#pragma unroll
    for (int ks = 0; ks < 2; ++ks) {
      bf16x8 af[4], bfr[4];
#pragma unroll
      for (int m = 0; m < 4; ++m) {
        int row = wr * 64 + m * 16 + (l & 15);
        int ph = (ks * 4 + (l >> 4)) ^ (row & 7);
        af[m] = *(const bf16x8*)&ldsA[row * 64 + ph * 8];
      }
#pragma unroll
      for (int n = 0; n < 4; ++n) {
        int row = wc * 64 + n * 16 + (l & 15);
        int ph = (ks * 4 + (l >> 4)) ^ (row & 7);
        bfr[n] = *(const bf16x8*)&ldsB[row * 64 + ph * 8];
      }
#pragma unroll
      for (int m = 0; m < 4; ++m)
#pragma unroll
        for (int n = 0; n < 4; ++n)
          acc[m][n] = __builtin_amdgcn_mfma_f32_16x16x32_bf16(af[m], bfr[n], acc[m][n], 0, 0, 0);
    }
    __syncthreads();
  }
#pragma unroll
  for (int m = 0; m < 4; ++m) {
#pragma unroll
    for (int j = 0; j < 4; ++j) {
      int row = ro0 + wr * 64 + m * 16 + (l >> 4) * 4 + j;
      float bv = bias[row];
#pragma unroll
      for (int n = 0; n < 4; ++n) {
        int col = co0 + wc * 64 + n * 16 + (l & 15);
        float val = acc[m][n][j] + bv;
        if (EPI == 0) {
          Co[(size_t)row * NB_ + col] = f2bf(val);
        } else {
          int bb = col >> 10, nn = col & 1023;
          size_t oi = (((size_t)(bb * C_ + row)) << 10) + nn;
          Fo[oi] = xres[oi] + val;
        }
      }
    }
  }
}

// ---- kernel 4: transpose q,k from (o, bn) to per-(b,h) (n, d) bf16 ----
__global__ __launch_bounds__(256) void transpose_qk_kernel(const u16* __restrict__ qkv,
                                                           u16* __restrict__ qT,
                                                           u16* __restrict__ kT) {
  int blk = blockIdx.x;
  int nt = blk & 15, h = (blk >> 4) & 7, sel = (blk >> 7) & 1, b = blk >> 8;
  const u16* src = qkv + (size_t)(sel * C_ + h * 64) * NB_ + (b << 10) + nt * 64;
  u16* dst = (sel ? kT : qT) + ((size_t)((b * 8 + h) << 10) + nt * 64) * 64;
  __shared__ u16 tile[64][68];
  int t = threadIdx.x;
  int r = t >> 2, c0 = (t & 3) * 16;
  const u16* sp = src + (size_t)r * NB_ + c0;
  uint4 a = *(const uint4*)sp;
  uint4 bb = *(const uint4*)(sp + 8);
  u16* tp = &tile[r][c0];
  uint2 t0 = {a.x, a.y}, t1 = {a.z, a.w}, t2 = {bb.x, bb.y}, t3 = {bb.z, bb.w};
  *(uint2*)tp = t0; *(uint2*)(tp + 4) = t1; *(uint2*)(tp + 8) = t2; *(uint2*)(tp + 12) = t3;
  __syncthreads();
  u32 pk[8];
#pragma unroll
  for (int q = 0; q < 8; ++q)
    pk[q] = (u32)tile[c0 + 2 * q][r] | ((u32)tile[c0 + 2 * q + 1][r] << 16);
  u16* dp = dst + (size_t)r * 64 + c0;
  uint4 o0 = {pk[0], pk[1], pk[2], pk[3]};
  uint4 o1 = {pk[4], pk[5], pk[6], pk[7]};
  *(uint4*)dp = o0;
  *(uint4*)(dp + 8) = o1;
}

// ---- kernel 5: flash attention; writes ao^T as (B*N, C) bf16 ----
__global__ __launch_bounds__(256) void attn_kernel(const u16* __restrict__ qT,
                                                   const u16* __restrict__ kT,
                                                   const u16* __restrict__ qkv,
                                                   u16* __restrict__ aoT) {
  int blk = blockIdx.x;
  int qt = blk & 15, h = (blk >> 4) & 7, b = blk >> 7;
  int bh = b * 8 + h;
  int t = threadIdx.x, l = t & 63, w = t >> 6;
  int n0 = qt * 64 + w * 16;  // each wave owns a 16-row q strip, fully independent
  const u16* qp = qT + ((size_t)(bh << 10) + n0 + (l & 15)) * 64 + (l >> 4) * 8;
  bf16x8 qf0 = *(const bf16x8*)qp;
  bf16x8 qf1 = *(const bf16x8*)(qp + 32);
  f32x4 accO[4];
#pragma unroll
  for (int dt = 0; dt < 4; ++dt) accO[dt] = {0.f, 0.f, 0.f, 0.f};
  float mrun[4] = {-1e30f, -1e30f, -1e30f, -1e30f};
  float lrun[4] = {0.f, 0.f, 0.f, 0.f};
  __shared__ u16 plds[4][16][68];  // stride 68: bank = 2*lane mod 32, conflict-free
  u16* pw = &plds[w][0][0];
  const u16* kb = kT + ((size_t)(bh << 10)) * 64 + (l & 15) * 64 + (l >> 4) * 8;
  const u16* vb = qkv + (size_t)(2 * C_ + h * 64 + (l & 15)) * NB_ + (b << 10) + (l >> 4) * 8;
  for (int mt = 0; mt < 16; ++mt) {
    f32x4 s[4];
#pragma unroll
    for (int j = 0; j < 4; ++j) s[j] = {0.f, 0.f, 0.f, 0.f};
#pragma unroll
    for (int ks = 0; ks < 2; ++ks) {
      bf16x8 qq = ks ? qf1 : qf0;
#pragma unroll
      for (int j = 0; j < 4; ++j) {
        bf16x8 kf = *(const bf16x8*)(kb + (size_t)(mt * 64 + j * 16) * 64 + ks * 32);
        s[j] = __builtin_amdgcn_mfma_f32_16x16x32_bf16(qq, kf, s[j], 0, 0, 0);
      }
    }
    float pm[4];
#pragma unroll
    for (int i = 0; i < 4; ++i) {
      s[0][i] *= 0.125f; s[1][i] *= 0.125f; s[2][i] *= 0.125f; s[3][i] *= 0.125f;
      pm[i] = fmaxf(fmaxf(s[0][i], s[1][i]), fmaxf(s[2][i], s[3][i]));
    }
#pragma unroll
    for (int msk = 1; msk < 16; msk <<= 1) {
#pragma unroll
      for (int i = 0; i < 4; ++i) pm[i] = fmaxf(pm[i], __shfl_xor(pm[i], msk, 64));
    }
    f32x4 pv[4];
    float rs[4];
#pragma unroll
    for (int i = 0; i < 4; ++i) {
      float newm = fmaxf(mrun[i], pm[i]);
      float scl = __expf(mrun[i] - newm);
      mrun[i] = newm;
      lrun[i] *= scl;
      accO[0][i] *= scl; accO[1][i] *= scl; accO[2][i] *= scl; accO[3][i] *= scl;
      float r0 = __expf(s[0][i] - newm);
      float r1 = __expf(s[1][i] - newm);
      float r2 = __expf(s[2][i] - newm);
      float r3 = __expf(s[3][i] - newm);
      pv[0][i] = r0; pv[1][i] = r1; pv[2][i] = r2; pv[3][i] = r3;
      rs[i] = (r0 + r1) + (r2 + r3);
    }
#pragma unroll
    for (int msk = 1; msk < 16; msk <<= 1) {
#pragma unroll
      for (int i = 0; i < 4; ++i) rs[i] += __shfl_xor(rs[i], msk, 64);
    }
#pragma unroll
    for (int i = 0; i < 4; ++i) lrun[i] += rs[i];
#pragma unroll
    for (int j = 0; j < 4; ++j)
#pragma unroll
      for (int i = 0; i < 4; ++i)
        pw[((l >> 4) * 4 + i) * 68 + j * 16 + (l & 15)] = f2bf(pv[j][i]);
#pragma unroll
    for (int ks2 = 0; ks2 < 2; ++ks2) {
      const u16* pr = pw + (l & 15) * 68 + ks2 * 32 + (l >> 4) * 8;
      union { uint2 u[2]; bf16x8 v; } pb;
      pb.u[0] = *(const uint2*)pr;
      pb.u[1] = *(const uint2*)(pr + 4);
#pragma unroll
      for (int dt = 0; dt < 4; ++dt) {
        bf16x8 vf = *(const bf16x8*)(vb + (size_t)(dt * 16) * NB_ + mt * 64 + ks2 * 32);
        accO[dt] = __builtin_amdgcn_mfma_f32_16x16x32_bf16(pb.v, vf, accO[dt], 0, 0, 0);
      }
    }
  }
  float inv[4];
#pragma unroll
  for (int i = 0; i < 4; ++i) inv[i] = 1.0f / lrun[i];
  u16* ob = aoT + ((size_t)((b << 10) + n0 + (l >> 4) * 4)) * C_ + h * 64 + (l & 15);
#pragma unroll
  for (int i = 0; i < 4; ++i)
#pragma unroll
    for (int dt = 0; dt < 4; ++dt)
      ob[(size_t)i * C_ + dt * 16] = f2bf(accO[dt][i] * inv[i]);
}

// ---- launcher ----
extern "C" void kernel_launch(void* const* d_in, const int* in_sizes, int n_in,
                              void* d_out, int out_size, void* d_ws, size_t ws_size,
                              hipStream_t stream) {
  const float* x = (const float*)d_in[0];
  const float* gamma = (const float*)d_in[1];
  const float* beta = (const float*)d_in[2];
  const float* qkv_w = (const float*)d_in[3];
  const float* qkv_b = (const float*)d_in[4];
  const float* proj_w = (const float*)d_in[5];
  const float* proj_b = (const float*)d_in[6];
  float* out = (float*)d_out;
  char* ws = (char*)d_ws;
  // workspace layout (bytes)
  u16* wq = (u16*)(ws);                      // 1536*512*2   = 1,572,864
  u16* wp = (u16*)(ws + 1572864);            // 512*512*2    =   524,288
  u16* ht = (u16*)(ws + 2097152);            // 16384*512*2  = 16,777,216 (reused as aoT)
  u16* qkvo = (u16*)(ws + 18874368);         // 1536*16384*2 = 50,331,648
  u16* qT = (u16*)(ws + 69206016);           // 16,777,216
  u16* kT = (u16*)(ws + 85983232);           // 16,777,216  -> total 102,760,448
  u16* aoT = ht;

  cast_bf16_kernel<<<3072, 256, 0, stream>>>(qkv_w, wq, M3_ * K_);
  cast_bf16_kernel<<<1024, 256, 0, stream>>>(proj_w, wp, C_ * K_);
  gnorm_kernel<<<512, 256, 0, stream>>>(x, gamma, beta, ht);
  gemm_kernel<0><<<dim3(128, 12), 256, 0, stream>>>(wq, ht, qkv_b, qkvo, nullptr, nullptr);
  transpose_qk_kernel<<<4096, 256, 0, stream>>>(qkvo, qT, kT);
  attn_kernel<<<2048, 256, 0, stream>>>(qT, kT, qkvo, aoT);
  gemm_kernel<1><<<dim3(128, 4), 256, 0, stream>>>(wp, aoT, proj_b, nullptr, x, out);
}

// Round 2
// 144.101 us; speedup vs baseline: 2.2234x; 2.2234x over previous
//
#include <hip/hip_runtime.h>

typedef unsigned short u16;
typedef unsigned int u32;
typedef __bf16 bf16x8 __attribute__((ext_vector_type(8)));
typedef float f32x4 __attribute__((ext_vector_type(4)));
typedef float f32x16 __attribute__((ext_vector_type(16)));

#define B_ 16
#define C_ 512
#define N_ 1024
#define NB_ 16384   // B_*N_
#define K_ 512
#define M3_ 1536
#define SCALE_Q 0.18033688011112042f  // 0.125 * log2(e)

// ---- helpers ----
__device__ __forceinline__ u16 f2bf(float f) {
  u32 u = __float_as_uint(f);
  u32 r = (u + 0x7FFFu + ((u >> 16) & 1u)) >> 16;  // RNE
  return (u16)r;
}

__device__ __forceinline__ void gl_lds16(const void* g, void* l) {
  __builtin_amdgcn_global_load_lds(
      (const __attribute__((address_space(1))) u32*)(uintptr_t)g,
      (__attribute__((address_space(3))) u32*)(u32)(uintptr_t)l, 16, 0, 0);
}

__device__ __forceinline__ u32 cvtpk(float lo, float hi) {
  u32 r;
  asm("v_cvt_pk_bf16_f32 %0, %1, %2" : "=v"(r) : "v"(lo), "v"(hi));
  return r;
}

__device__ __forceinline__ float exp2a(float x) {
  float r;
  asm("v_exp_f32 %0, %1" : "=v"(r) : "v"(x));
  return r;
}

// (a,b) -> a' = {a_lo, b_lo}, b' = {a_hi, b_hi}  (swap a's upper with b's lower)
__device__ __forceinline__ void plswap2(u32& a, u32& b) {
#if __has_builtin(__builtin_amdgcn_permlane32_swap)
  auto r = __builtin_amdgcn_permlane32_swap((int)a, (int)b, false, false);
  a = (u32)r[0];
  b = (u32)r[1];
#else
  asm("v_permlane32_swap_b32 %0, %1" : "+v"(a), "+v"(b));
#endif
}

__device__ __forceinline__ float xhalf_max(float x) {
  u32 a = __float_as_uint(x), b = a;
  plswap2(a, b);
  return fmaxf(__uint_as_float(a), __uint_as_float(b));
}

__device__ __forceinline__ float xhalf_sum(float x) {
  u32 a = __float_as_uint(x), b = a;
  plswap2(a, b);
  return __uint_as_float(a) + __uint_as_float(b);
}

// ---- kernel 1: fp32 -> bf16 cast for weights ----
__global__ __launch_bounds__(256) void cast_bf16_kernel(const float* __restrict__ src,
                                                        u16* __restrict__ dst, int n) {
  int i = blockIdx.x * 256 + threadIdx.x;
  if (i < n) dst[i] = f2bf(src[i]);
}

// ---- kernel 2: GroupNorm, writes h^T as (B*N, C) bf16 ----
__global__ __launch_bounds__(256) void gnorm_kernel(const float* __restrict__ x,
                                                    const float* __restrict__ gamma,
                                                    const float* __restrict__ beta,
                                                    u16* __restrict__ ht) {
  int blk = blockIdx.x;
  int b = blk >> 5, g = blk & 31;
  int t = threadIdx.x;
  const float* xb = x + ((size_t)(b * C_ + g * 16) << 10);
  float v[16][4];
  float s = 0.f, sq = 0.f;
#pragma unroll
  for (int cc = 0; cc < 16; ++cc) {
#pragma unroll
    for (int r = 0; r < 4; ++r) {
      float f = xb[cc * 1024 + r * 256 + t];
      v[cc][r] = f; s += f; sq += f * f;
    }
  }
#pragma unroll
  for (int m = 32; m >= 1; m >>= 1) { s += __shfl_xor(s, m, 64); sq += __shfl_xor(sq, m, 64); }
  __shared__ float red[8];
  int w = t >> 6;
  if ((t & 63) == 0) { red[w * 2] = s; red[w * 2 + 1] = sq; }
  __syncthreads();
  s = red[0] + red[2] + red[4] + red[6];
  sq = red[1] + red[3] + red[5] + red[7];
  float mean = s * (1.f / 16384.f);
  float var = sq * (1.f / 16384.f) - mean * mean;
  float rstd = rsqrtf(var + 1e-5f);
  float gm[16], bt[16];
#pragma unroll
  for (int cc = 0; cc < 16; ++cc) {
    gm[cc] = gamma[g * 16 + cc] * rstd;
    bt[cc] = beta[g * 16 + cc];
  }
  u16* hb = ht + ((size_t)(b << 10)) * C_ + g * 16;
#pragma unroll
  for (int r = 0; r < 4; ++r) {
    u32 pk[8];
#pragma unroll
    for (int q = 0; q < 8; ++q) {
      float f0 = (v[2 * q][r] - mean) * gm[2 * q] + bt[2 * q];
      float f1 = (v[2 * q + 1][r] - mean) * gm[2 * q + 1] + bt[2 * q + 1];
      pk[q] = (u32)f2bf(f0) | ((u32)f2bf(f1) << 16);
    }
    u16* dp = hb + (size_t)(r * 256 + t) * C_;
    uint4 a = {pk[0], pk[1], pk[2], pk[3]};
    uint4 b4 = {pk[4], pk[5], pk[6], pk[7]};
    *(uint4*)dp = a;
    *(uint4*)(dp + 8) = b4;
  }
}

// ---- GEMM: C[MxNB] = A[MxK] * BT[NBxK]^T ; 128x128 tile, BK=64, 4 waves ----
// EPI 0: out bf16 (o, bn) + bias, q-rows (<512) pre-scaled by SCALE_Q
// EPI 1: out = x + val + bias -> fp32 (b,c,n)
template <int EPI>
__global__ __launch_bounds__(256) void gemm_kernel(const u16* __restrict__ A,
                                                   const u16* __restrict__ BT,
                                                   const float* __restrict__ bias,
                                                   u16* __restrict__ Co,
                                                   const float* __restrict__ xres,
                                                   float* __restrict__ Fo) {
  __shared__ u16 ldsA[128 * 64];
  __shared__ u16 ldsB[128 * 64];
  int t = threadIdx.x;
  int l = t & 63, w = t >> 6;
  int wr = w >> 1, wc = w & 1;
  int ro0 = blockIdx.y * 128, co0 = blockIdx.x * 128;
  f32x4 acc[4][4];
#pragma unroll
  for (int m = 0; m < 4; ++m)
#pragma unroll
    for (int n = 0; n < 4; ++n) acc[m][n] = {0.f, 0.f, 0.f, 0.f};
  int srow = t >> 3, sg = t & 7;
  for (int kt = 0; kt < 8; ++kt) {
    int k0 = kt * 64;
#pragma unroll
    for (int i = 0; i < 4; ++i) {
      int row = i * 32 + srow;
      int gl = sg ^ (row & 7);  // pre-swizzled source -> swizzled linear LDS
      gl_lds16(A + (size_t)(ro0 + row) * K_ + k0 + gl * 8, ldsA + (i * 32 + w * 8) * 64);
      gl_lds16(BT + (size_t)(co0 + row) * K_ + k0 + gl * 8, ldsB + (i * 32 + w * 8) * 64);
    }
    __syncthreads();
#pragma unroll
    for (int ks = 0; ks < 2; ++ks) {
      bf16x8 af[4], bfr[4];
#pragma unroll
      for (int m = 0; m < 4; ++m) {
        int row = wr * 64 + m * 16 + (l & 15);
        int ph = (ks * 4 + (l >> 4)) ^ (row & 7);
        af[m] = *(const bf16x8*)&ldsA[row * 64 + ph * 8];
      }
#pragma unroll
      for (int n = 0; n < 4; ++n) {
        int row = wc * 64 + n * 16 + (l & 15);
        int ph = (ks * 4 + (l >> 4)) ^ (row & 7);
        bfr[n] = *(const bf16x8*)&ldsB[row * 64 + ph * 8];
      }
#pragma unroll
      for (int m = 0; m < 4; ++m)
#pragma unroll
        for (int n = 0; n < 4; ++n)
          acc[m][n] = __builtin_amdgcn_mfma_f32_16x16x32_bf16(af[m], bfr[n], acc[m][n], 0, 0, 0);
    }
    __syncthreads();
  }
#pragma unroll
  for (int m = 0; m < 4; ++m) {
#pragma unroll
    for (int j = 0; j < 4; ++j) {
      int row = ro0 + wr * 64 + m * 16 + (l >> 4) * 4 + j;
      float bv = bias[row];
#pragma unroll
      for (int n = 0; n < 4; ++n) {
        int col = co0 + wc * 64 + n * 16 + (l & 15);
        float val = acc[m][n][j] + bv;
        if (EPI == 0) {
          if (row < C_) val *= SCALE_Q;  // fold attention scale*log2e into q
          Co[(size_t)row * NB_ + col] = f2bf(val);
        } else {
          int bb = col >> 10, nn = col & 1023;
          size_t oi = (((size_t)(bb * C_ + row)) << 10) + nn;
          Fo[oi] = xres[oi] + val;
        }
      }
    }
  }
}

// ---- kernel 4: transpose q,k from (o, bn) to per-(b,h) (n, d) bf16 ----
__global__ __launch_bounds__(256) void transpose_qk_kernel(const u16* __restrict__ qkv,
                                                           u16* __restrict__ qT,
                                                           u16* __restrict__ kT) {
  int blk = blockIdx.x;
  int nt = blk & 15, h = (blk >> 4) & 7, sel = (blk >> 7) & 1, b = blk >> 8;
  const u16* src = qkv + (size_t)(sel * C_ + h * 64) * NB_ + (b << 10) + nt * 64;
  u16* dst = (sel ? kT : qT) + ((size_t)((b * 8 + h) << 10) + nt * 64) * 64;
  __shared__ u16 tile[64][68];
  int t = threadIdx.x;
  int r = t >> 2, c0 = (t & 3) * 16;
  const u16* sp = src + (size_t)r * NB_ + c0;
  uint4 a = *(const uint4*)sp;
  uint4 bb = *(const uint4*)(sp + 8);
  u16* tp = &tile[r][c0];
  uint2 t0 = {a.x, a.y}, t1 = {a.z, a.w}, t2 = {bb.x, bb.y}, t3 = {bb.z, bb.w};
  *(uint2*)tp = t0; *(uint2*)(tp + 4) = t1; *(uint2*)(tp + 8) = t2; *(uint2*)(tp + 12) = t3;
  __syncthreads();
  u32 pk[8];
#pragma unroll
  for (int q = 0; q < 8; ++q)
    pk[q] = (u32)tile[c0 + 2 * q][r] | ((u32)tile[c0 + 2 * q + 1][r] << 16);
  u16* dp = dst + (size_t)r * 64 + c0;
  uint4 o0 = {pk[0], pk[1], pk[2], pk[3]};
  uint4 o1 = {pk[4], pk[5], pk[6], pk[7]};
  *(uint4*)dp = o0;
  *(uint4*)(dp + 8) = o1;
}

// ---- kernel 5: flash attention, swapped-operand 32x32 MFMA, in-register softmax ----
// 4 waves/block, 32 q-rows/wave, KVBLK=64, K/V double-buffered in LDS (XOR swizzle).
__global__ __launch_bounds__(256) void attn_kernel(const u16* __restrict__ qT,
                                                   const u16* __restrict__ kT,
                                                   const u16* __restrict__ qkv,
                                                   u16* __restrict__ aoT) {
  __shared__ u16 lds[2][2][64 * 64];  // [buf][0=K (kk,d), 1=V^T (d,kk)]
  int bid = blockIdx.x;
  int wid = (bid & 7) * 128 + (bid >> 3);  // XCD swizzle: 2 (b,h) groups per XCD chunk
  int qt = wid & 7, h = (wid >> 3) & 7, b = wid >> 6;
  int bh = b * 8 + h;
  int t = threadIdx.x, l = t & 63, w = t >> 6;
  int lq = l & 31, hi = l >> 5;
  int q0 = qt * 128 + w * 32;

  // Q fragments: lane holds q = q0+lq, d = 16*kc + 8*hi + j (scale pre-folded)
  const u16* qbase = qT + ((size_t)(bh << 10) + q0 + lq) * 64 + hi * 8;
  bf16x8 qf[4];
#pragma unroll
  for (int kc = 0; kc < 4; ++kc) qf[kc] = *(const bf16x8*)(qbase + kc * 16);

  f32x16 accO[2];
#pragma unroll
  for (int dt = 0; dt < 2; ++dt)
#pragma unroll
    for (int r = 0; r < 16; ++r) accO[dt][r] = 0.f;
  float mrun = -1e30f, lsum = 0.f;

  const u16* kbase = kT + ((size_t)(bh << 10)) * 64;
  const u16* vbase = qkv + (size_t)(2 * C_ + h * 64) * NB_ + (b << 10);

  auto stage = [&](int buf, int mt) {
    int kv0 = mt * 64;
#pragma unroll
    for (int r = 0; r < 2; ++r) {
      int flat = r * 256 + w * 64 + l;
      int row = flat >> 3, g = flat & 7;
      int gs = (g ^ (row & 7)) * 8;
      gl_lds16(kbase + (size_t)(kv0 + row) * 64 + gs, &lds[buf][0][(r * 256 + w * 64) * 8]);
      gl_lds16(vbase + (size_t)row * NB_ + kv0 + gs, &lds[buf][1][(r * 256 + w * 64) * 8]);
    }
  };

  auto step = [&](int cur, int mt) {
    if (mt < 15) stage(cur ^ 1, mt + 1);
    const u16* Kl = lds[cur][0];
    const u16* Vl = lds[cur][1];
    // S^T = K * Q : chunk c covers kk = 32c..32c+31; lane: col q = lq, rows per C-layout
    f32x16 sc[2];
#pragma unroll
    for (int c = 0; c < 2; ++c) {
#pragma unroll
      for (int r = 0; r < 16; ++r) sc[c][r] = 0.f;
      int kk = c * 32 + lq;
#pragma unroll
      for (int kc = 0; kc < 4; ++kc) {
        int g = ((2 * kc + hi) ^ (kk & 7)) * 8;
        bf16x8 kf = *(const bf16x8*)(Kl + kk * 64 + g);
        sc[c] = __builtin_amdgcn_mfma_f32_32x32x16_bf16(kf, qf[kc], sc[c], 0, 0, 0);
      }
    }
    // row max: in-register tree + one half-swap (log2 units)
    float tm[8];
#pragma unroll
    for (int i = 0; i < 8; ++i)
      tm[i] = fmaxf(fmaxf(sc[0][i], sc[0][i + 8]), fmaxf(sc[1][i], sc[1][i + 8]));
#pragma unroll
    for (int s2 = 4; s2 >= 1; s2 >>= 1)
#pragma unroll
      for (int i = 0; i < s2; ++i) tm[i] = fmaxf(tm[i], tm[i + s2]);
    float tmax = xhalf_max(tm[0]);
    // defer-max: only rescale when the tile max grew past threshold
    if (__ballot(tmax > mrun + 10.0f)) {
      float newm = fmaxf(mrun, tmax);
      float scl = exp2a(mrun - newm);
      mrun = newm;
      lsum *= scl;
#pragma unroll
      for (int dt = 0; dt < 2; ++dt)
#pragma unroll
        for (int r = 0; r < 16; ++r) accO[dt][r] *= scl;
    }
    // P = exp2(S - m), accumulate row-sum (own-half partial)
    float ps = 0.f;
#pragma unroll
    for (int c = 0; c < 2; ++c)
#pragma unroll
      for (int r = 0; r < 16; ++r) {
        float e = exp2a(sc[c][r] - mrun);
        sc[c][r] = e;
        ps += e;
      }
    lsum += ps;
    // pack P^T into B-fragments in-register, PV accumulate
#pragma unroll
    for (int c = 0; c < 2; ++c) {
      u32 pk[8];
#pragma unroll
      for (int p = 0; p < 8; ++p) pk[p] = cvtpk(sc[c][2 * p], sc[c][2 * p + 1]);
#pragma unroll
      for (int cc = 0; cc < 2; ++cc) {
        u32 w0 = pk[cc * 4 + 0], w2 = pk[cc * 4 + 2];
        u32 w1 = pk[cc * 4 + 1], w3 = pk[cc * 4 + 3];
        plswap2(w0, w2);
        plswap2(w1, w3);
        union { u32 u[4]; bf16x8 v; } pf;
        pf.u[0] = w0; pf.u[1] = w1; pf.u[2] = w2; pf.u[3] = w3;
        int kcc = c * 2 + cc;
#pragma unroll
        for (int dt = 0; dt < 2; ++dt) {
          int d = dt * 32 + lq;
          int g = ((2 * kcc + hi) ^ (d & 7)) * 8;
          bf16x8 vf = *(const bf16x8*)(Vl + d * 64 + g);
          accO[dt] = __builtin_amdgcn_mfma_f32_32x32x16_bf16(vf, pf.v, accO[dt], 0, 0, 0);
        }
      }
    }
    __syncthreads();
  };

  stage(0, 0);
  __syncthreads();
#pragma unroll 1
  for (int mt2 = 0; mt2 < 8; ++mt2) {
    step(0, mt2 * 2);
    step(1, mt2 * 2 + 1);
  }

  float lfull = xhalf_sum(lsum);
  float inv = 1.0f / lfull;
  u16* ob = aoT + ((size_t)((b << 10) + q0 + lq)) * C_ + h * 64;
#pragma unroll
  for (int dt = 0; dt < 2; ++dt)
#pragma unroll
    for (int rg = 0; rg < 4; ++rg) {
      int d0 = dt * 32 + rg * 8 + hi * 4;
      u32 w0 = cvtpk(accO[dt][rg * 4 + 0] * inv, accO[dt][rg * 4 + 1] * inv);
      u32 w1 = cvtpk(accO[dt][rg * 4 + 2] * inv, accO[dt][rg * 4 + 3] * inv);
      uint2 o = {w0, w1};
      *(uint2*)(ob + d0) = o;
    }
}

// ---- launcher ----
extern "C" void kernel_launch(void* const* d_in, const int* in_sizes, int n_in,
                              void* d_out, int out_size, void* d_ws, size_t ws_size,
                              hipStream_t stream) {
  const float* x = (const float*)d_in[0];
  const float* gamma = (const float*)d_in[1];
  const float* beta = (const float*)d_in[2];
  const float* qkv_w = (const float*)d_in[3];
  const float* qkv_b = (const float*)d_in[4];
  const float* proj_w = (const float*)d_in[5];
  const float* proj_b = (const float*)d_in[6];
  float* out = (float*)d_out;
  char* ws = (char*)d_ws;
  u16* wq = (u16*)(ws);                      // 1,572,864
  u16* wp = (u16*)(ws + 1572864);            //   524,288
  u16* ht = (u16*)(ws + 2097152);            // 16,777,216 (reused as aoT)
  u16* qkvo = (u16*)(ws + 18874368);         // 50,331,648
  u16* qT = (u16*)(ws + 69206016);           // 16,777,216
  u16* kT = (u16*)(ws + 85983232);           // 16,777,216
  u16* aoT = ht;

  cast_bf16_kernel<<<3072, 256, 0, stream>>>(qkv_w, wq, M3_ * K_);
  cast_bf16_kernel<<<1024, 256, 0, stream>>>(proj_w, wp, C_ * K_);
  gnorm_kernel<<<512, 256, 0, stream>>>(x, gamma, beta, ht);
  gemm_kernel<0><<<dim3(128, 12), 256, 0, stream>>>(wq, ht, qkv_b, qkvo, nullptr, nullptr);
  transpose_qk_kernel<<<4096, 256, 0, stream>>>(qkvo, qT, kT);
  attn_kernel<<<1024, 256, 0, stream>>>(qT, kT, qkvo, aoT);
  gemm_kernel<1><<<dim3(128, 4), 256, 0, stream>>>(wp, aoT, proj_b, nullptr, x, out);
}

// Round 3
// 138.750 us; speedup vs baseline: 2.3092x; 1.0386x over previous
//
#include <hip/hip_runtime.h>

typedef unsigned short u16;
typedef unsigned int u32;
typedef __bf16 bf16x8 __attribute__((ext_vector_type(8)));
typedef float f32x4 __attribute__((ext_vector_type(4)));
typedef float f32x16 __attribute__((ext_vector_type(16)));

#define B_ 16
#define C_ 512
#define N_ 1024
#define NB_ 16384   // B_*N_
#define K_ 512
#define M3_ 1536
#define SCALE_Q 0.18033688011112042f  // 0.125 * log2(e)

// ---- helpers ----
__device__ __forceinline__ u16 f2bf(float f) {
  u32 u = __float_as_uint(f);
  u32 r = (u + 0x7FFFu + ((u >> 16) & 1u)) >> 16;  // RNE
  return (u16)r;
}

__device__ __forceinline__ void gl_lds16(const void* g, void* l) {
  __builtin_amdgcn_global_load_lds(
      (const __attribute__((address_space(1))) u32*)(uintptr_t)g,
      (__attribute__((address_space(3))) u32*)(u32)(uintptr_t)l, 16, 0, 0);
}

__device__ __forceinline__ u32 cvtpk(float lo, float hi) {
  u32 r;
  asm("v_cvt_pk_bf16_f32 %0, %1, %2" : "=v"(r) : "v"(lo), "v"(hi));
  return r;
}

__device__ __forceinline__ float exp2a(float x) {
  float r;
  asm("v_exp_f32 %0, %1" : "=v"(r) : "v"(x));
  return r;
}

// (a,b) -> a' = {a_lo, b_lo}, b' = {a_hi, b_hi}
__device__ __forceinline__ void plswap2(u32& a, u32& b) {
#if __has_builtin(__builtin_amdgcn_permlane32_swap)
  auto r = __builtin_amdgcn_permlane32_swap((int)a, (int)b, false, false);
  a = (u32)r[0];
  b = (u32)r[1];
#else
  asm("v_permlane32_swap_b32 %0, %1" : "+v"(a), "+v"(b));
#endif
}

__device__ __forceinline__ float xhalf_sum(float x) {
  u32 a = __float_as_uint(x), b = a;
  plswap2(a, b);
  return __uint_as_float(a) + __uint_as_float(b);
}

// bank-conflict-free granule swizzle: rows differing by 8 hit different bank groups
__device__ __forceinline__ int swz(int row) {
  return (row & 7) ^ (((row >> 3) & 1) << 2);
}

// ---- kernel 1: fp32 -> bf16 cast for weights ----
__global__ __launch_bounds__(256) void cast_bf16_kernel(const float* __restrict__ src,
                                                        u16* __restrict__ dst, int n) {
  int i = blockIdx.x * 256 + threadIdx.x;
  if (i < n) dst[i] = f2bf(src[i]);
}

// ---- kernel 2: GroupNorm, writes h^T as (B*N, C) bf16 ----
__global__ __launch_bounds__(256) void gnorm_kernel(const float* __restrict__ x,
                                                    const float* __restrict__ gamma,
                                                    const float* __restrict__ beta,
                                                    u16* __restrict__ ht) {
  int blk = blockIdx.x;
  int b = blk >> 5, g = blk & 31;
  int t = threadIdx.x;
  const float* xb = x + ((size_t)(b * C_ + g * 16) << 10);
  float v[16][4];
  float s = 0.f, sq = 0.f;
#pragma unroll
  for (int cc = 0; cc < 16; ++cc) {
#pragma unroll
    for (int r = 0; r < 4; ++r) {
      float f = xb[cc * 1024 + r * 256 + t];
      v[cc][r] = f; s += f; sq += f * f;
    }
  }
#pragma unroll
  for (int m = 32; m >= 1; m >>= 1) { s += __shfl_xor(s, m, 64); sq += __shfl_xor(sq, m, 64); }
  __shared__ float red[8];
  int w = t >> 6;
  if ((t & 63) == 0) { red[w * 2] = s; red[w * 2 + 1] = sq; }
  __syncthreads();
  s = red[0] + red[2] + red[4] + red[6];
  sq = red[1] + red[3] + red[5] + red[7];
  float mean = s * (1.f / 16384.f);
  float var = sq * (1.f / 16384.f) - mean * mean;
  float rstd = rsqrtf(var + 1e-5f);
  float gm[16], bt[16];
#pragma unroll
  for (int cc = 0; cc < 16; ++cc) {
    gm[cc] = gamma[g * 16 + cc] * rstd;
    bt[cc] = beta[g * 16 + cc];
  }
  u16* hb = ht + ((size_t)(b << 10)) * C_ + g * 16;
#pragma unroll
  for (int r = 0; r < 4; ++r) {
    u32 pk[8];
#pragma unroll
    for (int q = 0; q < 8; ++q) {
      float f0 = (v[2 * q][r] - mean) * gm[2 * q] + bt[2 * q];
      float f1 = (v[2 * q + 1][r] - mean) * gm[2 * q + 1] + bt[2 * q + 1];
      pk[q] = (u32)f2bf(f0) | ((u32)f2bf(f1) << 16);
    }
    u16* dp = hb + (size_t)(r * 256 + t) * C_;
    uint4 a = {pk[0], pk[1], pk[2], pk[3]};
    uint4 b4 = {pk[4], pk[5], pk[6], pk[7]};
    *(uint4*)dp = a;
    *(uint4*)(dp + 8) = b4;
  }
}

// ---- GEMM: C[MxNB] = A[MxK] * BT[NBxK]^T ; 128x128 tile, BK=64, 4 waves ----
template <int EPI>
__global__ __launch_bounds__(256) void gemm_kernel(const u16* __restrict__ A,
                                                   const u16* __restrict__ BT,
                                                   const float* __restrict__ bias,
                                                   u16* __restrict__ Co,
                                                   const float* __restrict__ xres,
                                                   float* __restrict__ Fo) {
  __shared__ u16 ldsA[128 * 64];
  __shared__ u16 ldsB[128 * 64];
  int t = threadIdx.x;
  int l = t & 63, w = t >> 6;
  int wr = w >> 1, wc = w & 1;
  int ro0 = blockIdx.y * 128, co0 = blockIdx.x * 128;
  f32x4 acc[4][4];
#pragma unroll
  for (int m = 0; m < 4; ++m)
#pragma unroll
    for (int n = 0; n < 4; ++n) acc[m][n] = {0.f, 0.f, 0.f, 0.f};
  int srow = t >> 3, sg = t & 7;
  for (int kt = 0; kt < 8; ++kt) {
    int k0 = kt * 64;
#pragma unroll
    for (int i = 0; i < 4; ++i) {
      int row = i * 32 + srow;
      int gl = sg ^ (row & 7);
      gl_lds16(A + (size_t)(ro0 + row) * K_ + k0 + gl * 8, ldsA + (i * 32 + w * 8) * 64);
      gl_lds16(BT + (size_t)(co0 + row) * K_ + k0 + gl * 8, ldsB + (i * 32 + w * 8) * 64);
    }
    __syncthreads();
#pragma unroll
    for (int ks = 0; ks < 2; ++ks) {
      bf16x8 af[4], bfr[4];
#pragma unroll
      for (int m = 0; m < 4; ++m) {
        int row = wr * 64 + m * 16 + (l & 15);
        int ph = (ks * 4 + (l >> 4)) ^ (row & 7);
        af[m] = *(const bf16x8*)&ldsA[row * 64 + ph * 8];
      }
#pragma unroll
      for (int n = 0; n < 4; ++n) {
        int row = wc * 64 + n * 16 + (l & 15);
        int ph = (ks * 4 + (l >> 4)) ^ (row & 7);
        bfr[n] = *(const bf16x8*)&ldsB[row * 64 + ph * 8];
      }
#pragma unroll
      for (int m = 0; m < 4; ++m)
#pragma unroll
        for (int n = 0; n < 4; ++n)
          acc[m][n] = __builtin_amdgcn_mfma_f32_16x16x32_bf16(af[m], bfr[n], acc[m][n], 0, 0, 0);
    }
    __syncthreads();
  }
#pragma unroll
  for (int m = 0; m < 4; ++m) {
#pragma unroll
    for (int j = 0; j < 4; ++j) {
      int row = ro0 + wr * 64 + m * 16 + (l >> 4) * 4 + j;
      float bv = bias[row];
#pragma unroll
      for (int n = 0; n < 4; ++n) {
        int col = co0 + wc * 64 + n * 16 + (l & 15);
        float val = acc[m][n][j] + bv;
        if (EPI == 0) {
          if (row < C_) val *= SCALE_Q;
          Co[(size_t)row * NB_ + col] = f2bf(val);
        } else {
          int bb = col >> 10, nn = col & 1023;
          size_t oi = (((size_t)(bb * C_ + row)) << 10) + nn;
          Fo[oi] = xres[oi] + val;
        }
      }
    }
  }
}

// ---- kernel 4: transpose q,k from (o, bn) to per-(b,h) (n, d) bf16 ----
__global__ __launch_bounds__(256) void transpose_qk_kernel(const u16* __restrict__ qkv,
                                                           u16* __restrict__ qT,
                                                           u16* __restrict__ kT) {
  int blk = blockIdx.x;
  int nt = blk & 15, h = (blk >> 4) & 7, sel = (blk >> 7) & 1, b = blk >> 8;
  const u16* src = qkv + (size_t)(sel * C_ + h * 64) * NB_ + (b << 10) + nt * 64;
  u16* dst = (sel ? kT : qT) + ((size_t)((b * 8 + h) << 10) + nt * 64) * 64;
  __shared__ u16 tile[64][68];
  int t = threadIdx.x;
  int r = t >> 2, c0 = (t & 3) * 16;
  const u16* sp = src + (size_t)r * NB_ + c0;
  uint4 a = *(const uint4*)sp;
  uint4 bb = *(const uint4*)(sp + 8);
  u16* tp = &tile[r][c0];
  uint2 t0 = {a.x, a.y}, t1 = {a.z, a.w}, t2 = {bb.x, bb.y}, t3 = {bb.z, bb.w};
  *(uint2*)tp = t0; *(uint2*)(tp + 4) = t1; *(uint2*)(tp + 8) = t2; *(uint2*)(tp + 12) = t3;
  __syncthreads();
  u32 pk[8];
#pragma unroll
  for (int q = 0; q < 8; ++q)
    pk[q] = (u32)tile[c0 + 2 * q][r] | ((u32)tile[c0 + 2 * q + 1][r] << 16);
  u16* dp = dst + (size_t)r * 64 + c0;
  uint4 o0 = {pk[0], pk[1], pk[2], pk[3]};
  uint4 o1 = {pk[4], pk[5], pk[6], pk[7]};
  *(uint4*)dp = o0;
  *(uint4*)(dp + 8) = o1;
}

// ---- kernel 5: flash attention ----
// 2 waves/block, 64 q-rows/wave (2x32 groups sharing every K/V fragment read),
// KVBLK=64 double-buffered in LDS, improved XOR swizzle, no online max
// (scores are in log2 units, |s| << 127; constant shift cancels in O = PV / sum P).
__global__ __launch_bounds__(128) void attn_kernel(const u16* __restrict__ qT,
                                                   const u16* __restrict__ kT,
                                                   const u16* __restrict__ qkv,
                                                   u16* __restrict__ aoT) {
  __shared__ u16 lds[2][2][64 * 64];  // [buf][0=K (kk,d), 1=V^T (d,kk)]
  int bid = blockIdx.x;
  int wid = (bid & 7) * 128 + (bid >> 3);  // XCD swizzle
  int qt = wid & 7, h = (wid >> 3) & 7, b = wid >> 6;
  int bh = b * 8 + h;
  int t = threadIdx.x, l = t & 63, w = t >> 6;
  int lq = l & 31, hi = l >> 5;
  int q0 = qt * 128 + w * 64;

  bf16x8 qf[2][4];
#pragma unroll
  for (int qg = 0; qg < 2; ++qg) {
    const u16* qbase = qT + ((size_t)(bh << 10) + q0 + qg * 32 + lq) * 64 + hi * 8;
#pragma unroll
    for (int kc = 0; kc < 4; ++kc) qf[qg][kc] = *(const bf16x8*)(qbase + kc * 16);
  }

  f32x16 accO[2][2];
#pragma unroll
  for (int qg = 0; qg < 2; ++qg)
#pragma unroll
    for (int dt = 0; dt < 2; ++dt)
#pragma unroll
      for (int r = 0; r < 16; ++r) accO[qg][dt][r] = 0.f;
  float lsum[2] = {0.f, 0.f};

  const u16* kbase = kT + ((size_t)(bh << 10)) * 64;
  const u16* vbase = qkv + (size_t)(2 * C_ + h * 64) * NB_ + (b << 10);

  auto stage = [&](int buf, int mt) {
    int kv0 = mt * 64;
#pragma unroll
    for (int r = 0; r < 4; ++r) {
      int flat = r * 128 + w * 64 + l;
      int row = flat >> 3, g = flat & 7;
      int gs = (g ^ swz(row)) * 8;
      gl_lds16(kbase + (size_t)(kv0 + row) * 64 + gs, &lds[buf][0][(r * 128 + w * 64) * 8]);
      gl_lds16(vbase + (size_t)row * NB_ + kv0 + gs, &lds[buf][1][(r * 128 + w * 64) * 8]);
    }
  };

  auto step = [&](int cur, int mt) {
    if (mt < 15) stage(cur ^ 1, mt + 1);
    const u16* Kl = lds[cur][0];
    const u16* Vl = lds[cur][1];
    // S^T = K * Q for both q-groups; each kf load feeds 2 MFMAs
    f32x16 sc[2][2];
#pragma unroll
    for (int c = 0; c < 2; ++c) {
      int kk = c * 32 + lq;
      int sw = swz(kk);
#pragma unroll
      for (int r = 0; r < 16; ++r) { sc[0][c][r] = 0.f; sc[1][c][r] = 0.f; }
#pragma unroll
      for (int kc = 0; kc < 4; ++kc) {
        int p = (2 * kc + hi) ^ sw;
        bf16x8 kf = *(const bf16x8*)(Kl + kk * 64 + p * 8);
        sc[0][c] = __builtin_amdgcn_mfma_f32_32x32x16_bf16(kf, qf[0][kc], sc[0][c], 0, 0, 0);
        sc[1][c] = __builtin_amdgcn_mfma_f32_32x32x16_bf16(kf, qf[1][kc], sc[1][c], 0, 0, 0);
      }
    }
    // P = exp2(S) (no max subtraction), pack P^T fragments in-register
    u32 pfu[2][4][4];
#pragma unroll
    for (int qg = 0; qg < 2; ++qg) {
      float ps = 0.f;
#pragma unroll
      for (int c = 0; c < 2; ++c)
#pragma unroll
        for (int r = 0; r < 16; ++r) {
          float e = exp2a(sc[qg][c][r]);
          sc[qg][c][r] = e;
          ps += e;
        }
      lsum[qg] += ps;
#pragma unroll
      for (int c = 0; c < 2; ++c) {
        u32 pk[8];
#pragma unroll
        for (int p = 0; p < 8; ++p) pk[p] = cvtpk(sc[qg][c][2 * p], sc[qg][c][2 * p + 1]);
#pragma unroll
        for (int cc = 0; cc < 2; ++cc) {
          u32 w0 = pk[cc * 4 + 0], w2 = pk[cc * 4 + 2];
          u32 w1 = pk[cc * 4 + 1], w3 = pk[cc * 4 + 3];
          plswap2(w0, w2);
          plswap2(w1, w3);
          int kcc = c * 2 + cc;
          pfu[qg][kcc][0] = w0; pfu[qg][kcc][1] = w1;
          pfu[qg][kcc][2] = w2; pfu[qg][kcc][3] = w3;
        }
      }
    }
    // PV: each vf load feeds 2 MFMAs
#pragma unroll
    for (int kcc = 0; kcc < 4; ++kcc) {
#pragma unroll
      for (int dt = 0; dt < 2; ++dt) {
        int d = dt * 32 + lq;
        int p = (2 * kcc + hi) ^ swz(d);
        bf16x8 vf = *(const bf16x8*)(Vl + d * 64 + p * 8);
        union { u32 u[4]; bf16x8 v; } pf0, pf1;
        pf0.u[0] = pfu[0][kcc][0]; pf0.u[1] = pfu[0][kcc][1];
        pf0.u[2] = pfu[0][kcc][2]; pf0.u[3] = pfu[0][kcc][3];
        pf1.u[0] = pfu[1][kcc][0]; pf1.u[1] = pfu[1][kcc][1];
        pf1.u[2] = pfu[1][kcc][2]; pf1.u[3] = pfu[1][kcc][3];
        accO[0][dt] = __builtin_amdgcn_mfma_f32_32x32x16_bf16(vf, pf0.v, accO[0][dt], 0, 0, 0);
        accO[1][dt] = __builtin_amdgcn_mfma_f32_32x32x16_bf16(vf, pf1.v, accO[1][dt], 0, 0, 0);
      }
    }
    __syncthreads();
  };

  stage(0, 0);
  __syncthreads();
#pragma unroll 1
  for (int mt2 = 0; mt2 < 8; ++mt2) {
    step(0, mt2 * 2);
    step(1, mt2 * 2 + 1);
  }

#pragma unroll
  for (int qg = 0; qg < 2; ++qg) {
    float inv = 1.0f / xhalf_sum(lsum[qg]);
    u16* ob = aoT + ((size_t)((b << 10) + q0 + qg * 32 + lq)) * C_ + h * 64;
#pragma unroll
    for (int dt = 0; dt < 2; ++dt)
#pragma unroll
      for (int rg = 0; rg < 4; ++rg) {
        int d0 = dt * 32 + rg * 8 + hi * 4;
        u32 w0 = cvtpk(accO[qg][dt][rg * 4 + 0] * inv, accO[qg][dt][rg * 4 + 1] * inv);
        u32 w1 = cvtpk(accO[qg][dt][rg * 4 + 2] * inv, accO[qg][dt][rg * 4 + 3] * inv);
        uint2 o = {w0, w1};
        *(uint2*)(ob + d0) = o;
      }
  }
}

// ---- launcher ----
extern "C" void kernel_launch(void* const* d_in, const int* in_sizes, int n_in,
                              void* d_out, int out_size, void* d_ws, size_t ws_size,
                              hipStream_t stream) {
  const float* x = (const float*)d_in[0];
  const float* gamma = (const float*)d_in[1];
  const float* beta = (const float*)d_in[2];
  const float* qkv_w = (const float*)d_in[3];
  const float* qkv_b = (const float*)d_in[4];
  const float* proj_w = (const float*)d_in[5];
  const float* proj_b = (const float*)d_in[6];
  float* out = (float*)d_out;
  char* ws = (char*)d_ws;
  u16* wq = (u16*)(ws);                      // 1,572,864
  u16* wp = (u16*)(ws + 1572864);            //   524,288
  u16* ht = (u16*)(ws + 2097152);            // 16,777,216 (reused as aoT)
  u16* qkvo = (u16*)(ws + 18874368);         // 50,331,648
  u16* qT = (u16*)(ws + 69206016);           // 16,777,216
  u16* kT = (u16*)(ws + 85983232);           // 16,777,216
  u16* aoT = ht;

  cast_bf16_kernel<<<3072, 256, 0, stream>>>(qkv_w, wq, M3_ * K_);
  cast_bf16_kernel<<<1024, 256, 0, stream>>>(proj_w, wp, C_ * K_);
  gnorm_kernel<<<512, 256, 0, stream>>>(x, gamma, beta, ht);
  gemm_kernel<0><<<dim3(128, 12), 256, 0, stream>>>(wq, ht, qkv_b, qkvo, nullptr, nullptr);
  transpose_qk_kernel<<<4096, 256, 0, stream>>>(qkvo, qT, kT);
  attn_kernel<<<1024, 128, 0, stream>>>(qT, kT, qkvo, aoT);
  gemm_kernel<1><<<dim3(128, 4), 256, 0, stream>>>(wp, aoT, proj_b, nullptr, x, out);
}

// Round 4
// 135.362 us; speedup vs baseline: 2.3670x; 1.0250x over previous
//
#include <hip/hip_runtime.h>

typedef unsigned short u16;
typedef unsigned int u32;
typedef __bf16 bf16x8 __attribute__((ext_vector_type(8)));
typedef float f32x4 __attribute__((ext_vector_type(4)));
typedef float f32x16 __attribute__((ext_vector_type(16)));

#define B_ 16
#define C_ 512
#define N_ 1024
#define NB_ 16384   // B_*N_
#define K_ 512
#define M3_ 1536
#define SCALE_Q 0.18033688011112042f  // 0.125 * log2(e)

// ---- helpers ----
__device__ __forceinline__ u16 f2bf(float f) {
  u32 u = __float_as_uint(f);
  u32 r = (u + 0x7FFFu + ((u >> 16) & 1u)) >> 16;  // RNE
  return (u16)r;
}

__device__ __forceinline__ void gl_lds16(const void* g, void* l) {
  __builtin_amdgcn_global_load_lds(
      (const __attribute__((address_space(1))) u32*)(uintptr_t)g,
      (__attribute__((address_space(3))) u32*)(u32)(uintptr_t)l, 16, 0, 0);
}

__device__ __forceinline__ u32 cvtpk(float lo, float hi) {
  u32 r;
  asm("v_cvt_pk_bf16_f32 %0, %1, %2" : "=v"(r) : "v"(lo), "v"(hi));
  return r;
}

__device__ __forceinline__ float exp2a(float x) {
  float r;
  asm("v_exp_f32 %0, %1" : "=v"(r) : "v"(x));
  return r;
}

// (a,b) -> a' = {a_lo, b_lo}, b' = {a_hi, b_hi}
__device__ __forceinline__ void plswap2(u32& a, u32& b) {
#if __has_builtin(__builtin_amdgcn_permlane32_swap)
  auto r = __builtin_amdgcn_permlane32_swap((int)a, (int)b, false, false);
  a = (u32)r[0];
  b = (u32)r[1];
#else
  asm("v_permlane32_swap_b32 %0, %1" : "+v"(a), "+v"(b));
#endif
}

__device__ __forceinline__ float xhalf_sum(float x) {
  u32 a = __float_as_uint(x), b = a;
  plswap2(a, b);
  return __uint_as_float(a) + __uint_as_float(b);
}

// ---- kernel 1: fp32 -> bf16 cast for weights ----
__global__ __launch_bounds__(256) void cast_bf16_kernel(const float* __restrict__ src,
                                                        u16* __restrict__ dst, int n) {
  int i = blockIdx.x * 256 + threadIdx.x;
  if (i < n) dst[i] = f2bf(src[i]);
}

// ---- kernel 2: GroupNorm, writes h^T as (B*N, C) bf16 ----
__global__ __launch_bounds__(256) void gnorm_kernel(const float* __restrict__ x,
                                                    const float* __restrict__ gamma,
                                                    const float* __restrict__ beta,
                                                    u16* __restrict__ ht) {
  int blk = blockIdx.x;
  int b = blk >> 5, g = blk & 31;
  int t = threadIdx.x;
  const float* xb = x + ((size_t)(b * C_ + g * 16) << 10);
  float v[16][4];
  float s = 0.f, sq = 0.f;
#pragma unroll
  for (int cc = 0; cc < 16; ++cc) {
#pragma unroll
    for (int r = 0; r < 4; ++r) {
      float f = xb[cc * 1024 + r * 256 + t];
      v[cc][r] = f; s += f; sq += f * f;
    }
  }
#pragma unroll
  for (int m = 32; m >= 1; m >>= 1) { s += __shfl_xor(s, m, 64); sq += __shfl_xor(sq, m, 64); }
  __shared__ float red[8];
  int w = t >> 6;
  if ((t & 63) == 0) { red[w * 2] = s; red[w * 2 + 1] = sq; }
  __syncthreads();
  s = red[0] + red[2] + red[4] + red[6];
  sq = red[1] + red[3] + red[5] + red[7];
  float mean = s * (1.f / 16384.f);
  float var = sq * (1.f / 16384.f) - mean * mean;
  float rstd = rsqrtf(var + 1e-5f);
  float gm[16], bt[16];
#pragma unroll
  for (int cc = 0; cc < 16; ++cc) {
    gm[cc] = gamma[g * 16 + cc] * rstd;
    bt[cc] = beta[g * 16 + cc];
  }
  u16* hb = ht + ((size_t)(b << 10)) * C_ + g * 16;
#pragma unroll
  for (int r = 0; r < 4; ++r) {
    u32 pk[8];
#pragma unroll
    for (int q = 0; q < 8; ++q) {
      float f0 = (v[2 * q][r] - mean) * gm[2 * q] + bt[2 * q];
      float f1 = (v[2 * q + 1][r] - mean) * gm[2 * q + 1] + bt[2 * q + 1];
      pk[q] = (u32)f2bf(f0) | ((u32)f2bf(f1) << 16);
    }
    u16* dp = hb + (size_t)(r * 256 + t) * C_;
    uint4 a = {pk[0], pk[1], pk[2], pk[3]};
    uint4 b4 = {pk[4], pk[5], pk[6], pk[7]};
    *(uint4*)dp = a;
    *(uint4*)(dp + 8) = b4;
  }
}

// ---- GEMM: C[MxNB] = A[MxK] * BT[NBxK]^T ; 128x128 tile, BK=64, 4 waves ----
// EPI 0: qkv GEMM. q,k bands (rows<1024) are stored TRANSPOSED per-(b,h) as
//        (n, d) bf16 into qTo/kTo (q pre-scaled); v band stored (o, bn) in Co.
// EPI 1: out = x + val + bias -> fp32 (b,c,n)
template <int EPI>
__global__ __launch_bounds__(256) void gemm_kernel(const u16* __restrict__ A,
                                                   const u16* __restrict__ BT,
                                                   const float* __restrict__ bias,
                                                   u16* __restrict__ Co,
                                                   u16* __restrict__ qTo,
                                                   u16* __restrict__ kTo,
                                                   const float* __restrict__ xres,
                                                   float* __restrict__ Fo) {
  __shared__ u16 ldsA[128 * 64];
  __shared__ u16 ldsB[128 * 64];
  int t = threadIdx.x;
  int l = t & 63, w = t >> 6;
  int wr = w >> 1, wc = w & 1;
  int ro0 = blockIdx.y * 128, co0 = blockIdx.x * 128;
  f32x4 acc[4][4];
#pragma unroll
  for (int m = 0; m < 4; ++m)
#pragma unroll
    for (int n = 0; n < 4; ++n) acc[m][n] = {0.f, 0.f, 0.f, 0.f};
  int srow = t >> 3, sg = t & 7;
  for (int kt = 0; kt < 8; ++kt) {
    int k0 = kt * 64;
#pragma unroll
    for (int i = 0; i < 4; ++i) {
      int row = i * 32 + srow;
      int gl = sg ^ (row & 7);
      gl_lds16(A + (size_t)(ro0 + row) * K_ + k0 + gl * 8, ldsA + (i * 32 + w * 8) * 64);
      gl_lds16(BT + (size_t)(co0 + row) * K_ + k0 + gl * 8, ldsB + (i * 32 + w * 8) * 64);
    }
    __syncthreads();
#pragma unroll
    for (int ks = 0; ks < 2; ++ks) {
      bf16x8 af[4], bfr[4];
#pragma unroll
      for (int m = 0; m < 4; ++m) {
        int row = wr * 64 + m * 16 + (l & 15);
        int ph = (ks * 4 + (l >> 4)) ^ (row & 7);
        af[m] = *(const bf16x8*)&ldsA[row * 64 + ph * 8];
      }
#pragma unroll
      for (int n = 0; n < 4; ++n) {
        int row = wc * 64 + n * 16 + (l & 15);
        int ph = (ks * 4 + (l >> 4)) ^ (row & 7);
        bfr[n] = *(const bf16x8*)&ldsB[row * 64 + ph * 8];
      }
#pragma unroll
      for (int m = 0; m < 4; ++m)
#pragma unroll
        for (int n = 0; n < 4; ++n)
          acc[m][n] = __builtin_amdgcn_mfma_f32_16x16x32_bf16(af[m], bfr[n], acc[m][n], 0, 0, 0);
    }
    __syncthreads();
  }
  if (EPI == 0 && ro0 < 1024) {
    // q/k band: transposed store into (b,h)(n,d) layout
    int sel = ro0 >> 9;
    u16* dstb = sel ? kTo : qTo;
    float scl = sel ? 1.f : SCALE_Q;
#pragma unroll
    for (int m = 0; m < 4; ++m) {
      int row0 = ro0 + wr * 64 + m * 16 + (l >> 4) * 4;
      int o = row0 & 511;
      int h = o >> 6, d0 = o & 63;
      float bv0 = bias[row0], bv1 = bias[row0 + 1];
      float bv2 = bias[row0 + 2], bv3 = bias[row0 + 3];
#pragma unroll
      for (int n = 0; n < 4; ++n) {
        int col = co0 + wc * 64 + n * 16 + (l & 15);
        int bb = col >> 10, nn = col & 1023;
        float v0 = (acc[m][n][0] + bv0) * scl;
        float v1 = (acc[m][n][1] + bv1) * scl;
        float v2 = (acc[m][n][2] + bv2) * scl;
        float v3 = (acc[m][n][3] + bv3) * scl;
        uint2 ov = {cvtpk(v0, v1), cvtpk(v2, v3)};
        *(uint2*)(dstb + ((size_t)((bb * 8 + h) << 10) + nn) * 64 + d0) = ov;
      }
    }
  } else {
#pragma unroll
    for (int m = 0; m < 4; ++m) {
#pragma unroll
      for (int j = 0; j < 4; ++j) {
        int row = ro0 + wr * 64 + m * 16 + (l >> 4) * 4 + j;
        float bv = bias[row];
#pragma unroll
        for (int n = 0; n < 4; ++n) {
          int col = co0 + wc * 64 + n * 16 + (l & 15);
          float val = acc[m][n][j] + bv;
          if (EPI == 0) {
            Co[(size_t)row * NB_ + col] = f2bf(val);
          } else {
            int bb = col >> 10, nn = col & 1023;
            size_t oi = (((size_t)(bb * C_ + row)) << 10) + nn;
            Fo[oi] = xres[oi] + val;
          }
        }
      }
    }
  }
}

// ---- kernel 4: flash attention, wave-autonomous (NO barriers) ----
// 2 independent waves/block; each wave owns 64 q-rows and a private 16KB
// double-buffered LDS K/V pair (KVBLK=32). Counted s_waitcnt vmcnt(8) keeps
// the next tile's 8 global_load_lds in flight across the whole step.
__global__ __launch_bounds__(128) void attn_kernel(const u16* __restrict__ qT,
                                                   const u16* __restrict__ kT,
                                                   const u16* __restrict__ qkv,
                                                   u16* __restrict__ aoT) {
  __shared__ u16 Kall[2][2][2048];  // [wave][buf][32 rows x 64 d]
  __shared__ u16 Vall[2][2][2048];  // [wave][buf][64 d-rows x 32 kv]
  int bid = blockIdx.x;
  int wid = (bid & 7) * 128 + (bid >> 3);  // XCD swizzle (1024 blocks, 8 XCDs)
  int qt2 = wid & 7, h = (wid >> 3) & 7, b = wid >> 6;
  int bh = b * 8 + h;
  int t = threadIdx.x, l = t & 63, w = t >> 6;
  int lq = l & 31, hi = l >> 5;
  int q0 = qt2 * 128 + w * 64;

  u16* Kw = &Kall[w][0][0];
  u16* Vw = &Vall[w][0][0];

  // Q fragments (scale pre-folded in qkv GEMM epilogue)
  bf16x8 qf[2][4];
#pragma unroll
  for (int qg = 0; qg < 2; ++qg) {
    const u16* qbase = qT + ((size_t)(bh << 10) + q0 + qg * 32 + lq) * 64 + hi * 8;
#pragma unroll
    for (int kc = 0; kc < 4; ++kc) qf[qg][kc] = *(const bf16x8*)(qbase + kc * 16);
  }

  f32x16 accO[2][2];
#pragma unroll
  for (int qg = 0; qg < 2; ++qg)
#pragma unroll
    for (int dt = 0; dt < 2; ++dt)
#pragma unroll
      for (int r = 0; r < 16; ++r) accO[qg][dt][r] = 0.f;
  float lsum[2] = {0.f, 0.f};

  // staging source pointers (per-lane offsets baked in; advance per tile)
  // K: instr i covers rows i*8+(l>>3), granule (l&7)^(row&7) -> (l&7)^((l>>3)&7)
  const u16* k_src = kT + ((size_t)(bh << 10) + (l >> 3)) * 64 + (((l & 7) ^ ((l >> 3) & 7)) * 8);
  // V: instr i covers d-rows i*16+(l>>2), granule (l&3)^((d>>1)&3) -> (l&3)^((l>>3)&3)
  const u16* v_src = qkv + (size_t)(2 * C_ + h * 64 + (l >> 2)) * NB_ + (b << 10) +
                     (((l & 3) ^ ((l >> 3) & 3)) * 8);

  // LDS read pointers (buf 0; buf 1 = +2048 elems)
  const u16* kfp[4];
#pragma unroll
  for (int kc = 0; kc < 4; ++kc)
    kfp[kc] = Kw + lq * 64 + (((2 * kc + hi) ^ (lq & 7)) * 8);
  const u16* vfp[4];
#pragma unroll
  for (int dt = 0; dt < 2; ++dt)
#pragma unroll
    for (int kcc = 0; kcc < 2; ++kcc)
      vfp[dt * 2 + kcc] = Vw + (dt * 32 + lq) * 32 + (((kcc * 2 + hi) ^ ((lq >> 1) & 3)) * 8);

  auto stage = [&](int buf) {
    u16* Kd = Kw + buf * 2048;
    u16* Vd = Vw + buf * 2048;
#pragma unroll
    for (int i = 0; i < 4; ++i) gl_lds16(k_src + i * 512, Kd + i * 512);
#pragma unroll
    for (int i = 0; i < 4; ++i) gl_lds16(v_src + (size_t)i * 16 * NB_, Vd + i * 512);
    k_src += 2048;  // 32 rows * 64
    v_src += 32;    // 32 kv columns
  };

  auto step = [&](int buf, bool dostage) {
    if (dostage) {
      stage(buf ^ 1);
      asm volatile("s_waitcnt vmcnt(8)" ::: "memory");
    } else {
      asm volatile("s_waitcnt vmcnt(0)" ::: "memory");
    }
    __builtin_amdgcn_sched_barrier(0);
    bf16x8 kf[4], vf[4];
#pragma unroll
    for (int kc = 0; kc < 4; ++kc) kf[kc] = *(const bf16x8*)(kfp[kc] + buf * 2048);
#pragma unroll
    for (int j = 0; j < 4; ++j) vf[j] = *(const bf16x8*)(vfp[j] + buf * 2048);
    f32x16 sc[2];
#pragma unroll
    for (int qg = 0; qg < 2; ++qg)
#pragma unroll
      for (int r = 0; r < 16; ++r) sc[qg][r] = 0.f;
    __builtin_amdgcn_s_setprio(1);
#pragma unroll
    for (int kc = 0; kc < 4; ++kc) {
      sc[0] = __builtin_amdgcn_mfma_f32_32x32x16_bf16(kf[kc], qf[0][kc], sc[0], 0, 0, 0);
      sc[1] = __builtin_amdgcn_mfma_f32_32x32x16_bf16(kf[kc], qf[1][kc], sc[1], 0, 0, 0);
    }
    __builtin_amdgcn_s_setprio(0);
    u32 pfu[2][2][4];
#pragma unroll
    for (int qg = 0; qg < 2; ++qg) {
      float ps = 0.f;
#pragma unroll
      for (int r = 0; r < 16; ++r) {
        float e = exp2a(sc[qg][r]);
        sc[qg][r] = e;
        ps += e;
      }
      lsum[qg] += ps;
      u32 pk[8];
#pragma unroll
      for (int p = 0; p < 8; ++p) pk[p] = cvtpk(sc[qg][2 * p], sc[qg][2 * p + 1]);
#pragma unroll
      for (int cc = 0; cc < 2; ++cc) {
        u32 w0 = pk[cc * 4 + 0], w2 = pk[cc * 4 + 2];
        u32 w1 = pk[cc * 4 + 1], w3 = pk[cc * 4 + 3];
        plswap2(w0, w2);
        plswap2(w1, w3);
        pfu[qg][cc][0] = w0; pfu[qg][cc][1] = w1;
        pfu[qg][cc][2] = w2; pfu[qg][cc][3] = w3;
      }
    }
    __builtin_amdgcn_s_setprio(1);
#pragma unroll
    for (int kcc = 0; kcc < 2; ++kcc)
#pragma unroll
      for (int dt = 0; dt < 2; ++dt) {
        bf16x8 vv = vf[dt * 2 + kcc];
#pragma unroll
        for (int qg = 0; qg < 2; ++qg) {
          union { u32 u[4]; bf16x8 v; } pf;
          pf.u[0] = pfu[qg][kcc][0]; pf.u[1] = pfu[qg][kcc][1];
          pf.u[2] = pfu[qg][kcc][2]; pf.u[3] = pfu[qg][kcc][3];
          accO[qg][dt] = __builtin_amdgcn_mfma_f32_32x32x16_bf16(vv, pf.v, accO[qg][dt], 0, 0, 0);
        }
      }
    __builtin_amdgcn_s_setprio(0);
  };

  stage(0);  // tile 0
#pragma unroll 1
  for (int s = 0; s < 15; ++s) {
    step(0, true);
    step(1, true);
  }
  step(0, true);   // tile 30, stages tile 31
  step(1, false);  // tile 31

#pragma unroll
  for (int qg = 0; qg < 2; ++qg) {
    float inv = 1.0f / xhalf_sum(lsum[qg]);
    u16* ob = aoT + ((size_t)((b << 10) + q0 + qg * 32 + lq)) * C_ + h * 64;
#pragma unroll
    for (int dt = 0; dt < 2; ++dt)
#pragma unroll
      for (int rg = 0; rg < 4; ++rg) {
        int d0 = dt * 32 + rg * 8 + hi * 4;
        u32 w0 = cvtpk(accO[qg][dt][rg * 4 + 0] * inv, accO[qg][dt][rg * 4 + 1] * inv);
        u32 w1 = cvtpk(accO[qg][dt][rg * 4 + 2] * inv, accO[qg][dt][rg * 4 + 3] * inv);
        uint2 o = {w0, w1};
        *(uint2*)(ob + d0) = o;
      }
  }
}

// ---- launcher ----
extern "C" void kernel_launch(void* const* d_in, const int* in_sizes, int n_in,
                              void* d_out, int out_size, void* d_ws, size_t ws_size,
                              hipStream_t stream) {
  const float* x = (const float*)d_in[0];
  const float* gamma = (const float*)d_in[1];
  const float* beta = (const float*)d_in[2];
  const float* qkv_w = (const float*)d_in[3];
  const float* qkv_b = (const float*)d_in[4];
  const float* proj_w = (const float*)d_in[5];
  const float* proj_b = (const float*)d_in[6];
  float* out = (float*)d_out;
  char* ws = (char*)d_ws;
  u16* wq = (u16*)(ws);                      // 1,572,864
  u16* wp = (u16*)(ws + 1572864);            //   524,288
  u16* ht = (u16*)(ws + 2097152);            // 16,777,216 (reused as aoT)
  u16* qkvo = (u16*)(ws + 18874368);         // 50,331,648 (only v band used)
  u16* qT = (u16*)(ws + 69206016);           // 16,777,216
  u16* kT = (u16*)(ws + 85983232);           // 16,777,216
  u16* aoT = ht;

  cast_bf16_kernel<<<3072, 256, 0, stream>>>(qkv_w, wq, M3_ * K_);
  cast_bf16_kernel<<<1024, 256, 0, stream>>>(proj_w, wp, C_ * K_);
  gnorm_kernel<<<512, 256, 0, stream>>>(x, gamma, beta, ht);
  gemm_kernel<0><<<dim3(128, 12), 256, 0, stream>>>(wq, ht, qkv_b, qkvo, qT, kT, nullptr, nullptr);
  attn_kernel<<<1024, 128, 0, stream>>>(qT, kT, qkvo, aoT);
  gemm_kernel<1><<<dim3(128, 4), 256, 0, stream>>>(wp, aoT, proj_b, nullptr, nullptr, nullptr, x, out);
}